// Round 1
// baseline (758.834 us; speedup 1.0000x reference)
//
#include <hip/hip_runtime.h>
#include <math.h>

#define NODES 20000
#define EDGES 320000
#define DIN   256
#define DD1   512
#define DD2   256
#define DOUT  64
#define EPSV  1e-5f

// ---------------- CSR build ----------------
__global__ void k_count(const int* __restrict__ dst, int* __restrict__ counts) {
    int e = blockIdx.x * blockDim.x + threadIdx.x;
    if (e < EDGES) atomicAdd(&counts[dst[e]], 1);
}

__global__ void k_scan(const int* __restrict__ counts, int* __restrict__ offs) {
    __shared__ int ssum[256];
    int t = threadIdx.x;
    const int chunk = (NODES + 255) / 256;
    int b = t * chunk, e = b + chunk;
    if (b > NODES) b = NODES;
    if (e > NODES) e = NODES;
    int s = 0;
    for (int i = b; i < e; i++) s += counts[i];
    ssum[t] = s;
    __syncthreads();
    if (t == 0) {
        int run = 0;
        for (int i = 0; i < 256; i++) { int v = ssum[i]; ssum[i] = run; run += v; }
        offs[NODES] = run;
    }
    __syncthreads();
    int run = ssum[t];
    for (int i = b; i < e; i++) { offs[i] = run; run += counts[i]; }
}

__global__ void k_scatter(const int* __restrict__ src, const int* __restrict__ dst,
                          const int* __restrict__ offs, int* __restrict__ cursor,
                          int* __restrict__ csr_src) {
    int e = blockIdx.x * blockDim.x + threadIdx.x;
    if (e < EDGES) {
        int d = dst[e];
        int pos = atomicAdd(&cursor[d], 1);
        csr_src[offs[d] + pos] = src[e];
    }
}

// ---------------- per-channel online softmax aggregation ----------------
// one wave per node; lane holds C/64 contiguous channels (float4 loads)
template <int C>
__global__ void k_aggregate(const float* __restrict__ x, const float* __restrict__ t,
                            const int* __restrict__ offs, const int* __restrict__ csr_src,
                            float* __restrict__ out) {
    constexpr int VPL = C / 64;
    int wave = (int)((blockIdx.x * (unsigned)blockDim.x + threadIdx.x) >> 6);
    int lane = threadIdx.x & 63;
    if (wave >= NODES) return;
    int beg = offs[wave], end = offs[wave + 1];
    int cbase = lane * VPL;
    float tv[VPL], m[VPL], l[VPL], s[VPL];
#pragma unroll
    for (int i = 0; i < VPL; i++) { tv[i] = t[cbase + i]; m[i] = -3.0e38f; l[i] = 0.f; s[i] = 0.f; }
    for (int k = beg; k < end; k++) {
        int sn = csr_src[k];
        const float4* xp = (const float4*)(x + (size_t)sn * C + cbase);
#pragma unroll
        for (int q = 0; q < VPL / 4; q++) {
            float4 v = xp[q];
            float vv[4] = {v.x, v.y, v.z, v.w};
#pragma unroll
            for (int j = 0; j < 4; j++) {
                int i = q * 4 + j;
                float xv = vv[j];
                float a = xv * tv[i];
                if (a > m[i]) {
                    float sc = __expf(m[i] - a);
                    l[i] = l[i] * sc + 1.f;
                    s[i] = s[i] * sc + xv;
                    m[i] = a;
                } else {
                    float p = __expf(a - m[i]);
                    l[i] += p;
                    s[i] += p * xv;
                }
            }
        }
    }
    bool has = end > beg;
    float* op = out + (size_t)wave * C + cbase;
#pragma unroll
    for (int q = 0; q < VPL / 4; q++) {
        float4 o;
        o.x = has ? s[q * 4 + 0] / l[q * 4 + 0] : 0.f;
        o.y = has ? s[q * 4 + 1] / l[q * 4 + 1] : 0.f;
        o.z = has ? s[q * 4 + 2] / l[q * 4 + 2] : 0.f;
        o.w = has ? s[q * 4 + 3] / l[q * 4 + 3] : 0.f;
        *(float4*)(op + q * 4) = o;
    }
}

// ---------------- dual fp32 GEMM: C = A1*B1 + A2*B2 + bias ----------------
// 64x64 tile / block of 256 threads, 4x4 per thread
template <int K, int NN>
__global__ __launch_bounds__(256) void k_gemm_dual(
    const float* __restrict__ A1, const float* __restrict__ B1,
    const float* __restrict__ A2, const float* __restrict__ B2,
    const float* __restrict__ bias, float* __restrict__ Co, int M) {
    __shared__ float As[16][68];
    __shared__ float Bs[16][68];
    int t = threadIdx.x;
    int tx = t & 15, ty = t >> 4;
    int m0 = blockIdx.x * 64;
    int n0 = blockIdx.y * 64;
    float acc[4][4] = {};
    for (int ph = 0; ph < 2; ph++) {
        const float* __restrict__ A = ph ? A2 : A1;
        const float* __restrict__ B = ph ? B2 : B1;
        for (int k0 = 0; k0 < K; k0 += 16) {
            {
                int r = t >> 2, c4 = t & 3;
                int m = m0 + r;
                float4 v = {0.f, 0.f, 0.f, 0.f};
                if (m < M) v = *(const float4*)(A + (size_t)m * K + k0 + c4 * 4);
                As[c4 * 4 + 0][r] = v.x;
                As[c4 * 4 + 1][r] = v.y;
                As[c4 * 4 + 2][r] = v.z;
                As[c4 * 4 + 3][r] = v.w;
            }
            {
                int kk = t >> 4, n4 = t & 15;
                float4 v = *(const float4*)(B + (size_t)(k0 + kk) * NN + n0 + n4 * 4);
                *(float4*)&Bs[kk][n4 * 4] = v;
            }
            __syncthreads();
#pragma unroll
            for (int k = 0; k < 16; k++) {
                float4 a = *(const float4*)&As[k][ty * 4];
                float4 b = *(const float4*)&Bs[k][tx * 4];
                float av[4] = {a.x, a.y, a.z, a.w};
                float bv[4] = {b.x, b.y, b.z, b.w};
#pragma unroll
                for (int ii = 0; ii < 4; ii++)
#pragma unroll
                    for (int jj = 0; jj < 4; jj++)
                        acc[ii][jj] = fmaf(av[ii], bv[jj], acc[ii][jj]);
            }
            __syncthreads();
        }
    }
    float4 bv = *(const float4*)(bias + n0 + tx * 4);
    float bvv[4] = {bv.x, bv.y, bv.z, bv.w};
#pragma unroll
    for (int ii = 0; ii < 4; ii++) {
        int m = m0 + ty * 4 + ii;
        if (m < M) {
            float4 o;
            o.x = acc[ii][0] + bvv[0];
            o.y = acc[ii][1] + bvv[1];
            o.z = acc[ii][2] + bvv[2];
            o.w = acc[ii][3] + bvv[3];
            *(float4*)(Co + (size_t)m * NN + n0 + tx * 4) = o;
        }
    }
}

// ---------------- graph-LN reductions ----------------
__global__ void k_reduce(const float* __restrict__ x, int n4, float* __restrict__ acc) {
    const float4* x4 = (const float4*)x;
    float s = 0.f, ss = 0.f;
    for (int i = blockIdx.x * blockDim.x + threadIdx.x; i < n4; i += gridDim.x * blockDim.x) {
        float4 v = x4[i];
        s += v.x + v.y + v.z + v.w;
        ss += v.x * v.x + v.y * v.y + v.z * v.z + v.w * v.w;
    }
    __shared__ float sh[256], sh2[256];
    sh[threadIdx.x] = s; sh2[threadIdx.x] = ss;
    __syncthreads();
    for (int o = 128; o > 0; o >>= 1) {
        if (threadIdx.x < o) { sh[threadIdx.x] += sh[threadIdx.x + o]; sh2[threadIdx.x] += sh2[threadIdx.x + o]; }
        __syncthreads();
    }
    if (threadIdx.x == 0) { atomicAdd(&acc[0], sh[0]); atomicAdd(&acc[1], sh2[0]); }
}

// graph LN: y = relu((x-mu)/(std+eps)*g[c]+b[c]); optional column-sum for mean-pool
// COLSUM requires C == blockDim.x == 256 (thread t always owns channel t)
template <int C, bool COLSUM>
__global__ void k_ln_relu(float* __restrict__ x, int n, const float* __restrict__ acc,
                          const float* __restrict__ g, const float* __restrict__ b,
                          float* __restrict__ colsum) {
    float mu = acc[0] / (float)n;
    float var = acc[1] / (float)n - mu * mu;
    var = var < 0.f ? 0.f : var;
    float inv = 1.0f / (sqrtf(var) + EPSV);
    float local = 0.f;
    int stride = gridDim.x * blockDim.x;
    for (int i = blockIdx.x * blockDim.x + threadIdx.x; i < n; i += stride) {
        int c = i & (C - 1);
        float y = (x[i] - mu) * inv * g[c] + b[c];
        y = fmaxf(y, 0.f);
        x[i] = y;
        if (COLSUM) local += y;
    }
    if (COLSUM) atomicAdd(&colsum[threadIdx.x], local);
}

// ---------------- head: mean-pool @ Wf + bf -> LN(64) -> relu ----------------
__global__ void k_final(const float* __restrict__ colsum, const float* __restrict__ Wf,
                        const float* __restrict__ bf, const float* __restrict__ gx,
                        const float* __restrict__ bx, float* __restrict__ out) {
    __shared__ float p[256];
    int t = threadIdx.x;
    p[t] = colsum[t] * (1.0f / (float)NODES);
    __syncthreads();
    if (t < 64) {
        float acc = bf[t];
        for (int c = 0; c < 256; c++) acc = fmaf(p[c], Wf[c * 64 + t], acc);
        float sum = acc;
        for (int o = 32; o > 0; o >>= 1) sum += __shfl_xor(sum, o);
        float mu = sum * (1.0f / 64.0f);
        float d = acc - mu;
        float vs = d * d;
        for (int o = 32; o > 0; o >>= 1) vs += __shfl_xor(vs, o);
        float var = vs * (1.0f / 64.0f);
        float y = d * rsqrtf(var + EPSV) * gx[t] + bx[t];
        out[t] = fmaxf(y, 0.f);
    }
}

extern "C" void kernel_launch(void* const* d_in, const int* in_sizes, int n_in,
                              void* d_out, int out_size, void* d_ws, size_t ws_size,
                              hipStream_t stream) {
    const float* x   = (const float*)d_in[0];
    const int*   ei  = (const int*)d_in[1];
    const float* t1  = (const float*)d_in[2];
    const float* Wl1 = (const float*)d_in[3];
    const float* bl1 = (const float*)d_in[4];
    const float* Wr1 = (const float*)d_in[5];
    const float* g1  = (const float*)d_in[6];
    const float* be1 = (const float*)d_in[7];
    const float* t2  = (const float*)d_in[8];
    const float* Wl2 = (const float*)d_in[9];
    const float* bl2 = (const float*)d_in[10];
    const float* Wr2 = (const float*)d_in[11];
    const float* g2  = (const float*)d_in[12];
    const float* be2 = (const float*)d_in[13];
    const float* Wf  = (const float*)d_in[14];
    const float* bf  = (const float*)d_in[15];
    const float* gx  = (const float*)d_in[16];
    const float* bx  = (const float*)d_in[17];
    float* out = (float*)d_out;

    char* ws = (char*)d_ws;
    size_t off = 0;
    auto alloc = [&](size_t bytes) { size_t o = off; off = (off + bytes + 511) & ~511ull; return o; };
    size_t o_counts = alloc((size_t)NODES * 4);
    size_t o_cursor = alloc((size_t)NODES * 4);
    size_t o_acc    = alloc(4 * 4);
    size_t o_colsum = alloc(256 * 4);
    size_t zero_bytes = off;                       // counts+cursor+acc+colsum
    size_t o_offs = alloc((size_t)(NODES + 1) * 4);
    size_t o_csrc = alloc((size_t)EDGES * 4);
    size_t o_bufA = alloc((size_t)NODES * 256 * 4);  // agg1, later h2
    size_t o_bufB = alloc((size_t)NODES * 512 * 4);  // h1
    size_t o_bufC = alloc((size_t)NODES * 512 * 4);  // agg2

    int*   counts = (int*)(ws + o_counts);
    int*   cursor = (int*)(ws + o_cursor);
    float* acc    = (float*)(ws + o_acc);      // [0,1]=L1 sum/sumsq, [2,3]=L2
    float* colsum = (float*)(ws + o_colsum);
    int*   offs   = (int*)(ws + o_offs);
    int*   csrc   = (int*)(ws + o_csrc);
    float* agg1   = (float*)(ws + o_bufA);
    float* h1     = (float*)(ws + o_bufB);
    float* agg2   = (float*)(ws + o_bufC);
    float* h2     = (float*)(ws + o_bufA);     // reuse agg1's space

    const int* src = ei;
    const int* dst = ei + EDGES;

    hipMemsetAsync(ws, 0, zero_bytes, stream);

    k_count<<<(EDGES + 255) / 256, 256, 0, stream>>>(dst, counts);
    k_scan<<<1, 256, 0, stream>>>(counts, offs);
    k_scatter<<<(EDGES + 255) / 256, 256, 0, stream>>>(src, dst, offs, cursor, csrc);

    // ----- layer 1 -----
    k_aggregate<256><<<(NODES + 3) / 4, 256, 0, stream>>>(x, t1, offs, csrc, agg1);
    k_gemm_dual<256, 512><<<dim3((NODES + 63) / 64, 512 / 64), 256, 0, stream>>>(
        agg1, Wl1, x, Wr1, bl1, h1, NODES);
    k_reduce<<<1024, 256, 0, stream>>>(h1, NODES * 512 / 4, acc);
    k_ln_relu<512, false><<<2048, 256, 0, stream>>>(h1, NODES * 512, acc, g1, be1, nullptr);

    // ----- layer 2 -----
    k_aggregate<512><<<(NODES + 3) / 4, 256, 0, stream>>>(h1, t2, offs, csrc, agg2);
    k_gemm_dual<512, 256><<<dim3((NODES + 63) / 64, 256 / 64), 256, 0, stream>>>(
        agg2, Wl2, h1, Wr2, bl2, h2, NODES);
    k_reduce<<<1024, 256, 0, stream>>>(h2, NODES * 256 / 4, acc + 2);
    k_ln_relu<256, true><<<2048, 256, 0, stream>>>(h2, NODES * 256, acc + 2, g2, be2, colsum);

    // ----- head -----
    k_final<<<1, 256, 0, stream>>>(colsum, Wf, bf, gx, bx, out);
}

// Round 2
// 433.358 us; speedup vs baseline: 1.7511x; 1.7511x over previous
//
#include <hip/hip_runtime.h>
#include <math.h>

#define NODES 20000
#define EDGES 320000
#define EPSV  1e-5f

typedef short bf16x8 __attribute__((ext_vector_type(8)));
typedef float f32x4  __attribute__((ext_vector_type(4)));

__device__ __forceinline__ unsigned short f2bf(float f) {
    unsigned int u = __float_as_uint(f);
    u = (u + 0x7fffu + ((u >> 16) & 1u)) >> 16;
    return (unsigned short)u;
}
__device__ __forceinline__ float bf2f(unsigned short h) {
    return __uint_as_float(((unsigned int)h) << 16);
}

// ---------------- CSR build ----------------
__global__ void k_count(const int* __restrict__ dst, int* __restrict__ counts) {
    int e = blockIdx.x * blockDim.x + threadIdx.x;
    if (e < EDGES) atomicAdd(&counts[dst[e]], 1);
}

__global__ void k_scan(const int* __restrict__ counts, int* __restrict__ offs) {
    __shared__ int ssum[256];
    int t = threadIdx.x;
    const int chunk = (NODES + 255) / 256;
    int b = t * chunk, e = b + chunk;
    if (b > NODES) b = NODES;
    if (e > NODES) e = NODES;
    int s = 0;
    for (int i = b; i < e; i++) s += counts[i];
    ssum[t] = s;
    __syncthreads();
    if (t == 0) {
        int run = 0;
        for (int i = 0; i < 256; i++) { int v = ssum[i]; ssum[i] = run; run += v; }
        offs[NODES] = run;
    }
    __syncthreads();
    int run = ssum[t];
    for (int i = b; i < e; i++) { offs[i] = run; run += counts[i]; }
}

__global__ void k_scatter(const int* __restrict__ src, const int* __restrict__ dst,
                          const int* __restrict__ offs, int* __restrict__ cursor,
                          int* __restrict__ csr_src) {
    int e = blockIdx.x * blockDim.x + threadIdx.x;
    if (e < EDGES) {
        int d = dst[e];
        int pos = atomicAdd(&cursor[d], 1);
        csr_src[offs[d] + pos] = src[e];
    }
}

// ---------------- prep: fp32 -> bf16 cast ----------------
__global__ void k_cast(const float* __restrict__ in, unsigned short* __restrict__ out) {
    int i = (blockIdx.x * blockDim.x + threadIdx.x) * 4;
    float4 v = *(const float4*)(in + i);
    out[i + 0] = f2bf(v.x); out[i + 1] = f2bf(v.y);
    out[i + 2] = f2bf(v.z); out[i + 3] = f2bf(v.w);
}

// ---------------- prep: W [K][N] fp32 -> Wt [N][K] bf16 (LDS tile transpose) ----
template <int K, int N>
__global__ void k_transpose(const float* __restrict__ W, unsigned short* __restrict__ Wt) {
    __shared__ float tile[32][33];
    int tx = threadIdx.x, ty = threadIdx.y;   // blockDim (32,8)
    int n0 = blockIdx.x * 32, k0 = blockIdx.y * 32;
#pragma unroll
    for (int j = 0; j < 4; j++)
        tile[ty + j * 8][tx] = W[(size_t)(k0 + ty + j * 8) * N + n0 + tx];
    __syncthreads();
#pragma unroll
    for (int j = 0; j < 4; j++)
        Wt[(size_t)(n0 + ty + j * 8) * K + k0 + tx] = f2bf(tile[tx][ty + j * 8]);
}

// ---------------- per-channel online softmax aggregation (bf16 in/out) --------
// one wave per node; lane holds C/64 contiguous channels, one vector load/edge
template <int C>
__global__ void k_agg(const unsigned short* __restrict__ xb, const float* __restrict__ tt,
                      const int* __restrict__ offs, const int* __restrict__ csr,
                      unsigned short* __restrict__ out) {
    constexpr int VPL = C / 64;
    typedef unsigned short usv __attribute__((ext_vector_type(VPL)));
    int wave = (int)((blockIdx.x * (unsigned)blockDim.x + threadIdx.x) >> 6);
    int lane = threadIdx.x & 63;
    if (wave >= NODES) return;
    int beg = offs[wave], end = offs[wave + 1];
    int cb = lane * VPL;
    float tv[VPL], m[VPL], l[VPL], s[VPL];
#pragma unroll
    for (int i = 0; i < VPL; i++) { tv[i] = tt[cb + i]; m[i] = -3.0e38f; l[i] = 0.f; s[i] = 0.f; }
    for (int k = beg; k < end; k++) {
        int sn = csr[k];
        usv v = *(const usv*)(xb + (size_t)sn * C + cb);
#pragma unroll
        for (int i = 0; i < VPL; i++) {
            float xv = bf2f(v[i]);
            float a = xv * tv[i];
            float nm = fmaxf(m[i], a);
            float p = __expf(a - nm);
            float sc = __expf(m[i] - nm);
            l[i] = l[i] * sc + p;
            s[i] = s[i] * sc + p * xv;
            m[i] = nm;
        }
    }
    bool has = end > beg;
    usv o;
#pragma unroll
    for (int i = 0; i < VPL; i++) o[i] = f2bf(has ? s[i] / l[i] : 0.f);
    *(usv*)(out + (size_t)wave * C + cb) = o;
}

// ---------------- dual bf16 MFMA GEMM: C = A1*B1t^T + A2*B2t^T + bias ---------
// 128x128 tile, BK=32, 4 waves (2x2), each wave 4x4 grid of 16x16x32 mfma.
// B supplied pre-transposed bf16 [N][K]. Output bf16 (pre-LN); LN sum/sumsq
// fused into epilogue via 2 atomics/block.
template <int K, int NT>
__global__ __launch_bounds__(256) void k_gemm_mfma(
    const unsigned short* __restrict__ A1, const unsigned short* __restrict__ B1t,
    const unsigned short* __restrict__ A2, const unsigned short* __restrict__ B2t,
    const float* __restrict__ bias, unsigned short* __restrict__ Co, int M,
    float* __restrict__ stat) {
    __shared__ short As[128 * 40];   // rows padded to 40 shorts (80B) -> conflict-free
    __shared__ short Bs[128 * 40];
    __shared__ float rs[256], rq[256];

    int t = threadIdx.x;
    int m0 = blockIdx.x * 128, n0 = blockIdx.y * 128;
    int wv = t >> 6, lane = t & 63;
    int wm = wv & 1, wn = wv >> 1;
    int lm = lane & 15, quad = lane >> 4;
    int sr = t >> 2;             // staging row (0..63), +64 on 2nd iter
    int sk = (t & 3) * 8;        // staging k-offset {0,8,16,24}

    f32x4 acc[4][4] = {};

    for (int ph = 0; ph < 2; ph++) {
        const unsigned short* __restrict__ A  = ph ? A2 : A1;
        const unsigned short* __restrict__ Bt = ph ? B2t : B1t;
        for (int k0 = 0; k0 < K; k0 += 32) {
#pragma unroll
            for (int it = 0; it < 2; it++) {
                int r = sr + it * 64;
                int mm = m0 + r;
                bf16x8 va;
#pragma unroll
                for (int j = 0; j < 8; j++) va[j] = 0;
                if (mm < M) va = *(const bf16x8*)(A + (size_t)mm * K + k0 + sk);
                *(bf16x8*)&As[r * 40 + sk] = va;
                bf16x8 vb = *(const bf16x8*)(Bt + (size_t)(n0 + r) * K + k0 + sk);
                *(bf16x8*)&Bs[r * 40 + sk] = vb;
            }
            __syncthreads();
            bf16x8 af[4], bfr[4];
#pragma unroll
            for (int i = 0; i < 4; i++) {
                af[i]  = *(const bf16x8*)&As[(wm * 64 + i * 16 + lm) * 40 + quad * 8];
                bfr[i] = *(const bf16x8*)&Bs[(wn * 64 + i * 16 + lm) * 40 + quad * 8];
            }
#pragma unroll
            for (int mi = 0; mi < 4; mi++)
#pragma unroll
                for (int nj = 0; nj < 4; nj++)
                    acc[mi][nj] = __builtin_amdgcn_mfma_f32_16x16x32_bf16(
                        af[mi], bfr[nj], acc[mi][nj], 0, 0, 0);
            __syncthreads();
        }
    }

    // epilogue: +bias, store bf16, fused LN sum/sumsq
    float sum = 0.f, ss = 0.f;
#pragma unroll
    for (int mi = 0; mi < 4; mi++) {
        int rb = m0 + wm * 64 + mi * 16 + quad * 4;
#pragma unroll
        for (int nj = 0; nj < 4; nj++) {
            int col = n0 + wn * 64 + nj * 16 + lm;
            float bb = bias[col];
#pragma unroll
            for (int rg = 0; rg < 4; rg++) {
                int row = rb + rg;
                if (row < M) {
                    float y = acc[mi][nj][rg] + bb;
                    Co[(size_t)row * NT + col] = f2bf(y);
                    sum += y; ss += y * y;
                }
            }
        }
    }
    rs[t] = sum; rq[t] = ss;
    __syncthreads();
    for (int o = 128; o > 0; o >>= 1) {
        if (t < o) { rs[t] += rs[t + o]; rq[t] += rq[t + o]; }
        __syncthreads();
    }
    if (t == 0) { atomicAdd(&stat[0], rs[0]); atomicAdd(&stat[1], rq[0]); }
}

// ---------------- graph-LN + ReLU, in-place bf16, vectorized x8 --------------
template <int C>
__global__ void k_ln_relu_b(unsigned short* __restrict__ h, int n,
                            const float* __restrict__ st,
                            const float* __restrict__ g, const float* __restrict__ b) {
    typedef unsigned short us8 __attribute__((ext_vector_type(8)));
    float mu = st[0] / (float)n;
    float var = st[1] / (float)n - mu * mu;
    var = var < 0.f ? 0.f : var;
    float inv = 1.0f / (sqrtf(var) + EPSV);
    int i8 = (blockIdx.x * blockDim.x + threadIdx.x) * 8;
    if (i8 >= n) return;
    int c = i8 & (C - 1);
    us8 v = *(const us8*)(h + i8);
    us8 o;
#pragma unroll
    for (int j = 0; j < 8; j++) {
        float y = (bf2f(v[j]) - mu) * inv * g[c + j] + b[c + j];
        o[j] = f2bf(fmaxf(y, 0.f));
    }
    *(us8*)(h + i8) = o;
}

// graph-LN + ReLU + column-sum only (layer 2; h2 not needed afterwards)
__global__ void k_ln_colsum(const unsigned short* __restrict__ h, int n,
                            const float* __restrict__ st,
                            const float* __restrict__ g, const float* __restrict__ b,
                            float* __restrict__ colsum) {
    float mu = st[0] / (float)n;
    float var = st[1] / (float)n - mu * mu;
    var = var < 0.f ? 0.f : var;
    float inv = 1.0f / (sqrtf(var) + EPSV);
    int t = threadIdx.x;
    float gv = g[t], bv = b[t];
    float local = 0.f;
    int stride = gridDim.x * blockDim.x;   // multiple of 256 -> channel == t always
    for (int i = blockIdx.x * blockDim.x + t; i < n; i += stride) {
        float y = (bf2f(h[i]) - mu) * inv * gv + bv;
        local += fmaxf(y, 0.f);
    }
    atomicAdd(&colsum[t], local);
}

// ---------------- head: mean-pool @ Wf + bf -> LN(64) -> relu ----------------
__global__ void k_final(const float* __restrict__ colsum, const float* __restrict__ Wf,
                        const float* __restrict__ bf, const float* __restrict__ gx,
                        const float* __restrict__ bx, float* __restrict__ out) {
    __shared__ float p[256];
    int t = threadIdx.x;
    p[t] = colsum[t] * (1.0f / (float)NODES);
    __syncthreads();
    if (t < 64) {
        float acc = bf[t];
        for (int c = 0; c < 256; c++) acc = fmaf(p[c], Wf[c * 64 + t], acc);
        float sum = acc;
        for (int o = 32; o > 0; o >>= 1) sum += __shfl_xor(sum, o);
        float mu = sum * (1.0f / 64.0f);
        float d = acc - mu;
        float vs = d * d;
        for (int o = 32; o > 0; o >>= 1) vs += __shfl_xor(vs, o);
        float var = vs * (1.0f / 64.0f);
        float y = d * rsqrtf(var + EPSV) * gx[t] + bx[t];
        out[t] = fmaxf(y, 0.f);
    }
}

extern "C" void kernel_launch(void* const* d_in, const int* in_sizes, int n_in,
                              void* d_out, int out_size, void* d_ws, size_t ws_size,
                              hipStream_t stream) {
    const float* x   = (const float*)d_in[0];
    const int*   ei  = (const int*)d_in[1];
    const float* t1  = (const float*)d_in[2];
    const float* Wl1 = (const float*)d_in[3];
    const float* bl1 = (const float*)d_in[4];
    const float* Wr1 = (const float*)d_in[5];
    const float* g1  = (const float*)d_in[6];
    const float* be1 = (const float*)d_in[7];
    const float* t2  = (const float*)d_in[8];
    const float* Wl2 = (const float*)d_in[9];
    const float* bl2 = (const float*)d_in[10];
    const float* Wr2 = (const float*)d_in[11];
    const float* g2  = (const float*)d_in[12];
    const float* be2 = (const float*)d_in[13];
    const float* Wf  = (const float*)d_in[14];
    const float* bf  = (const float*)d_in[15];
    const float* gx  = (const float*)d_in[16];
    const float* bx  = (const float*)d_in[17];
    float* out = (float*)d_out;

    char* ws = (char*)d_ws;
    size_t off = 0;
    auto alloc = [&](size_t bytes) { size_t o = off; off = (off + bytes + 511) & ~511ull; return o; };
    size_t o_counts = alloc((size_t)NODES * 4);
    size_t o_cursor = alloc((size_t)NODES * 4);
    size_t o_acc    = alloc(4 * 4);
    size_t o_colsum = alloc(256 * 4);
    size_t zero_bytes = off;
    size_t o_offs = alloc((size_t)(NODES + 1) * 4);
    size_t o_csrc = alloc((size_t)EDGES * 4);
    size_t o_w1l  = alloc((size_t)512 * 256 * 2);
    size_t o_w1r  = alloc((size_t)512 * 256 * 2);
    size_t o_w2l  = alloc((size_t)256 * 512 * 2);
    size_t o_w2r  = alloc((size_t)256 * 512 * 2);
    size_t o_bufX = alloc((size_t)NODES * 256 * 2);  // xb, later h2_pre (bf16)
    size_t o_agg  = alloc((size_t)NODES * 512 * 2);  // agg1b (first half) / agg2b
    size_t o_h1   = alloc((size_t)NODES * 512 * 2);  // h1 pre-LN bf16, LN'd in place

    int*   counts = (int*)(ws + o_counts);
    int*   cursor = (int*)(ws + o_cursor);
    float* acc    = (float*)(ws + o_acc);      // [0,1]=L1 stats, [2,3]=L2 stats
    float* colsum = (float*)(ws + o_colsum);
    int*   offs   = (int*)(ws + o_offs);
    int*   csrc   = (int*)(ws + o_csrc);
    unsigned short* w1lt = (unsigned short*)(ws + o_w1l);
    unsigned short* w1rt = (unsigned short*)(ws + o_w1r);
    unsigned short* w2lt = (unsigned short*)(ws + o_w2l);
    unsigned short* w2rt = (unsigned short*)(ws + o_w2r);
    unsigned short* xb   = (unsigned short*)(ws + o_bufX);
    unsigned short* h2p  = (unsigned short*)(ws + o_bufX);  // reuse after xb dead
    unsigned short* aggb = (unsigned short*)(ws + o_agg);
    unsigned short* h1   = (unsigned short*)(ws + o_h1);

    const int* src = ei;
    const int* dst = ei + EDGES;

    hipMemsetAsync(ws, 0, zero_bytes, stream);

    // CSR + precasts
    k_count<<<(EDGES + 255) / 256, 256, 0, stream>>>(dst, counts);
    k_scan<<<1, 256, 0, stream>>>(counts, offs);
    k_scatter<<<(EDGES + 255) / 256, 256, 0, stream>>>(src, dst, offs, cursor, csrc);
    k_cast<<<NODES * 256 / 4 / 256, 256, 0, stream>>>(x, xb);
    k_transpose<256, 512><<<dim3(16, 8), dim3(32, 8), 0, stream>>>(Wl1, w1lt);
    k_transpose<256, 512><<<dim3(16, 8), dim3(32, 8), 0, stream>>>(Wr1, w1rt);
    k_transpose<512, 256><<<dim3(8, 16), dim3(32, 8), 0, stream>>>(Wl2, w2lt);
    k_transpose<512, 256><<<dim3(8, 16), dim3(32, 8), 0, stream>>>(Wr2, w2rt);

    // ----- layer 1 -----
    k_agg<256><<<(NODES + 3) / 4, 256, 0, stream>>>(xb, t1, offs, csrc, aggb);
    k_gemm_mfma<256, 512><<<dim3((NODES + 127) / 128, 4), 256, 0, stream>>>(
        aggb, w1lt, xb, w1rt, bl1, h1, NODES, acc);
    k_ln_relu_b<512><<<NODES * 512 / 8 / 256, 256, 0, stream>>>(h1, NODES * 512, acc, g1, be1);

    // ----- layer 2 -----
    k_agg<512><<<(NODES + 3) / 4, 256, 0, stream>>>(h1, t2, offs, csrc, aggb);
    k_gemm_mfma<512, 256><<<dim3((NODES + 127) / 128, 2), 256, 0, stream>>>(
        aggb, w2lt, h1, w2rt, bl2, h2p, NODES, acc + 2);
    k_ln_colsum<<<1024, 256, 0, stream>>>(h2p, NODES * 256, acc + 2, g2, be2, colsum);

    // ----- head -----
    k_final<<<1, 256, 0, stream>>>(colsum, Wf, bf, gx, bx, out);
}

// Round 3
// 372.140 us; speedup vs baseline: 2.0391x; 1.1645x over previous
//
#include <hip/hip_runtime.h>
#include <math.h>

#define NODES 20000
#define EDGES 320000
#define EPSV  1e-5f
#define LOG2E 1.4426950408889634f

typedef short bf16x8 __attribute__((ext_vector_type(8)));
typedef float f32x4  __attribute__((ext_vector_type(4)));

__device__ __forceinline__ unsigned short f2bf(float f) {
    unsigned int u = __float_as_uint(f);
    u = (u + 0x7fffu + ((u >> 16) & 1u)) >> 16;
    return (unsigned short)u;
}
__device__ __forceinline__ float bf2f(unsigned short h) {
    return __uint_as_float(((unsigned int)h) << 16);
}

// ---------------- CSR build ----------------
__global__ void k_count(const int* __restrict__ dst, int* __restrict__ counts) {
    int e = blockIdx.x * blockDim.x + threadIdx.x;
    if (e < EDGES) atomicAdd(&counts[dst[e]], 1);
}

__global__ void k_scan(const int* __restrict__ counts, int* __restrict__ offs) {
    __shared__ int ssum[256];
    int t = threadIdx.x;
    const int chunk = (NODES + 255) / 256;
    int b = t * chunk, e = b + chunk;
    if (b > NODES) b = NODES;
    if (e > NODES) e = NODES;
    int s = 0;
    for (int i = b; i < e; i++) s += counts[i];
    ssum[t] = s;
    __syncthreads();
    if (t == 0) {
        int run = 0;
        for (int i = 0; i < 256; i++) { int v = ssum[i]; ssum[i] = run; run += v; }
        offs[NODES] = run;
    }
    __syncthreads();
    int run = ssum[t];
    for (int i = b; i < e; i++) { offs[i] = run; run += counts[i]; }
}

__global__ void k_scatter(const int* __restrict__ src, const int* __restrict__ dst,
                          const int* __restrict__ offs, int* __restrict__ cursor,
                          int* __restrict__ csr_src) {
    int e = blockIdx.x * blockDim.x + threadIdx.x;
    if (e < EDGES) {
        int d = dst[e];
        int pos = atomicAdd(&cursor[d], 1);
        csr_src[offs[d] + pos] = src[e];
    }
}

// ---------------- prep: fp32 -> bf16 cast ----------------
__global__ void k_cast(const float* __restrict__ in, unsigned short* __restrict__ out) {
    int i = (blockIdx.x * blockDim.x + threadIdx.x) * 4;
    float4 v = *(const float4*)(in + i);
    out[i + 0] = f2bf(v.x); out[i + 1] = f2bf(v.y);
    out[i + 2] = f2bf(v.z); out[i + 3] = f2bf(v.w);
}

// ------- prep: all four W [K][N] fp32 -> Wt [N][K] bf16, one dispatch --------
__global__ void k_transpose_all(const float* __restrict__ Wl1, const float* __restrict__ Wr1,
                                const float* __restrict__ Wl2, const float* __restrict__ Wr2,
                                unsigned short* __restrict__ o1l, unsigned short* __restrict__ o1r,
                                unsigned short* __restrict__ o2l, unsigned short* __restrict__ o2r) {
    __shared__ float tile[32][33];
    int z = blockIdx.z;
    const float* W = (z == 0) ? Wl1 : (z == 1) ? Wr1 : (z == 2) ? Wl2 : Wr2;
    unsigned short* Wt = (z == 0) ? o1l : (z == 1) ? o1r : (z == 2) ? o2l : o2r;
    int K = (z < 2) ? 256 : 512, N = (z < 2) ? 512 : 256;
    int nb = N / 32;
    int n0 = (blockIdx.x % nb) * 32, k0 = (blockIdx.x / nb) * 32;
    int tx = threadIdx.x, ty = threadIdx.y;   // blockDim (32,8)
#pragma unroll
    for (int j = 0; j < 4; j++)
        tile[ty + j * 8][tx] = W[(size_t)(k0 + ty + j * 8) * N + n0 + tx];
    __syncthreads();
#pragma unroll
    for (int j = 0; j < 4; j++)
        Wt[(size_t)(n0 + ty + j * 8) * K + k0 + tx] = f2bf(tile[tx][ty + j * 8]);
}

// ------- per-channel softmax aggregation, un-stabilized (inputs bounded) -----
// one wave per node; lane holds C/64 contiguous channels; sum exp2(x*t') and
// exp2(x*t')*x per channel; edge-pair unroll for load overlap.
template <int C>
__global__ void k_agg(const unsigned short* __restrict__ xb, const float* __restrict__ tt,
                      const int* __restrict__ offs, const int* __restrict__ csr,
                      unsigned short* __restrict__ out) {
    constexpr int VPL = C / 64;
    typedef unsigned short usv __attribute__((ext_vector_type(VPL)));
    int wave = (int)((blockIdx.x * (unsigned)blockDim.x + threadIdx.x) >> 6);
    int lane = threadIdx.x & 63;
    if (wave >= NODES) return;
    int beg = offs[wave], end = offs[wave + 1];
    int cb = lane * VPL;
    float tl[VPL], l[VPL], s[VPL];
#pragma unroll
    for (int i = 0; i < VPL; i++) { tl[i] = tt[cb + i] * LOG2E; l[i] = 0.f; s[i] = 0.f; }
    int k = beg;
    for (; k + 1 < end; k += 2) {
        int sn0 = csr[k], sn1 = csr[k + 1];
        usv v0 = *(const usv*)(xb + (size_t)sn0 * C + cb);
        usv v1 = *(const usv*)(xb + (size_t)sn1 * C + cb);
#pragma unroll
        for (int i = 0; i < VPL; i++) {
            float x0 = bf2f(v0[i]);
            float x1 = bf2f(v1[i]);
            float p0 = __builtin_amdgcn_exp2f(x0 * tl[i]);
            float p1 = __builtin_amdgcn_exp2f(x1 * tl[i]);
            l[i] += p0;
            s[i] = fmaf(p0, x0, s[i]);
            l[i] += p1;
            s[i] = fmaf(p1, x1, s[i]);
        }
    }
    if (k < end) {
        int sn = csr[k];
        usv v = *(const usv*)(xb + (size_t)sn * C + cb);
#pragma unroll
        for (int i = 0; i < VPL; i++) {
            float xv = bf2f(v[i]);
            float p = __builtin_amdgcn_exp2f(xv * tl[i]);
            l[i] += p;
            s[i] = fmaf(p, xv, s[i]);
        }
    }
    bool has = end > beg;
    usv o;
#pragma unroll
    for (int i = 0; i < VPL; i++) o[i] = f2bf(has ? s[i] / l[i] : 0.f);
    *(usv*)(out + (size_t)wave * C + cb) = o;
}

// ---------------- dual bf16 MFMA GEMM: C = A1*B1t^T + A2*B2t^T + bias ---------
// 128x128 tile, BK=32, 4 waves (2x2), each wave 4x4 grid of 16x16x32 mfma.
// B supplied pre-transposed bf16 [N][K]. Output bf16 (pre-LN); LN sum/sumsq
// fused into epilogue via 2 atomics/block.
template <int K, int NT>
__global__ __launch_bounds__(256) void k_gemm_mfma(
    const unsigned short* __restrict__ A1, const unsigned short* __restrict__ B1t,
    const unsigned short* __restrict__ A2, const unsigned short* __restrict__ B2t,
    const float* __restrict__ bias, unsigned short* __restrict__ Co, int M,
    float* __restrict__ stat) {
    __shared__ short As[128 * 40];   // rows padded to 40 shorts (80B) -> conflict-free
    __shared__ short Bs[128 * 40];
    __shared__ float rs[256], rq[256];

    int t = threadIdx.x;
    int m0 = blockIdx.x * 128, n0 = blockIdx.y * 128;
    int wv = t >> 6, lane = t & 63;
    int wm = wv & 1, wn = wv >> 1;
    int lm = lane & 15, quad = lane >> 4;
    int sr = t >> 2;             // staging row (0..63), +64 on 2nd iter
    int sk = (t & 3) * 8;        // staging k-offset {0,8,16,24}

    f32x4 acc[4][4] = {};

    for (int ph = 0; ph < 2; ph++) {
        const unsigned short* __restrict__ A  = ph ? A2 : A1;
        const unsigned short* __restrict__ Bt = ph ? B2t : B1t;
        for (int k0 = 0; k0 < K; k0 += 32) {
#pragma unroll
            for (int it = 0; it < 2; it++) {
                int r = sr + it * 64;
                int mm = m0 + r;
                bf16x8 va;
#pragma unroll
                for (int j = 0; j < 8; j++) va[j] = 0;
                if (mm < M) va = *(const bf16x8*)(A + (size_t)mm * K + k0 + sk);
                *(bf16x8*)&As[r * 40 + sk] = va;
                bf16x8 vb = *(const bf16x8*)(Bt + (size_t)(n0 + r) * K + k0 + sk);
                *(bf16x8*)&Bs[r * 40 + sk] = vb;
            }
            __syncthreads();
            bf16x8 af[4], bfr[4];
#pragma unroll
            for (int i = 0; i < 4; i++) {
                af[i]  = *(const bf16x8*)&As[(wm * 64 + i * 16 + lm) * 40 + quad * 8];
                bfr[i] = *(const bf16x8*)&Bs[(wn * 64 + i * 16 + lm) * 40 + quad * 8];
            }
#pragma unroll
            for (int mi = 0; mi < 4; mi++)
#pragma unroll
                for (int nj = 0; nj < 4; nj++)
                    acc[mi][nj] = __builtin_amdgcn_mfma_f32_16x16x32_bf16(
                        af[mi], bfr[nj], acc[mi][nj], 0, 0, 0);
            __syncthreads();
        }
    }

    // epilogue: +bias, store bf16, fused LN sum/sumsq
    float sum = 0.f, ss = 0.f;
#pragma unroll
    for (int mi = 0; mi < 4; mi++) {
        int rb = m0 + wm * 64 + mi * 16 + quad * 4;
#pragma unroll
        for (int nj = 0; nj < 4; nj++) {
            int col = n0 + wn * 64 + nj * 16 + lm;
            float bb = bias[col];
#pragma unroll
            for (int rg = 0; rg < 4; rg++) {
                int row = rb + rg;
                if (row < M) {
                    float y = acc[mi][nj][rg] + bb;
                    Co[(size_t)row * NT + col] = f2bf(y);
                    sum += y; ss += y * y;
                }
            }
        }
    }
    rs[t] = sum; rq[t] = ss;
    __syncthreads();
    for (int o = 128; o > 0; o >>= 1) {
        if (t < o) { rs[t] += rs[t + o]; rq[t] += rq[t + o]; }
        __syncthreads();
    }
    if (t == 0) { atomicAdd(&stat[0], rs[0]); atomicAdd(&stat[1], rq[0]); }
}

// ---------------- graph-LN + ReLU, in-place bf16, vectorized x8 --------------
template <int C>
__global__ void k_ln_relu_b(unsigned short* __restrict__ h, int n,
                            const float* __restrict__ st,
                            const float* __restrict__ g, const float* __restrict__ b) {
    typedef unsigned short us8 __attribute__((ext_vector_type(8)));
    float mu = st[0] / (float)n;
    float var = st[1] / (float)n - mu * mu;
    var = var < 0.f ? 0.f : var;
    float inv = 1.0f / (sqrtf(var) + EPSV);
    int i8 = (blockIdx.x * blockDim.x + threadIdx.x) * 8;
    if (i8 >= n) return;
    int c = i8 & (C - 1);
    us8 v = *(const us8*)(h + i8);
    us8 o;
#pragma unroll
    for (int j = 0; j < 8; j++) {
        float y = (bf2f(v[j]) - mu) * inv * g[c + j] + b[c + j];
        o[j] = f2bf(fmaxf(y, 0.f));
    }
    *(us8*)(h + i8) = o;
}

// graph-LN + ReLU + column-sum only (layer 2; h2 not needed afterwards)
__global__ void k_ln_colsum(const unsigned short* __restrict__ h, int n,
                            const float* __restrict__ st,
                            const float* __restrict__ g, const float* __restrict__ b,
                            float* __restrict__ colsum) {
    float mu = st[0] / (float)n;
    float var = st[1] / (float)n - mu * mu;
    var = var < 0.f ? 0.f : var;
    float inv = 1.0f / (sqrtf(var) + EPSV);
    int t = threadIdx.x;
    float gv = g[t], bv = b[t];
    float local = 0.f;
    int stride = gridDim.x * blockDim.x;   // multiple of 256 -> channel == t always
    for (int i = blockIdx.x * blockDim.x + t; i < n; i += stride) {
        float y = (bf2f(h[i]) - mu) * inv * gv + bv;
        local += fmaxf(y, 0.f);
    }
    atomicAdd(&colsum[t], local);
}

// ---------------- head: mean-pool @ Wf + bf -> LN(64) -> relu ----------------
__global__ void k_final(const float* __restrict__ colsum, const float* __restrict__ Wf,
                        const float* __restrict__ bf, const float* __restrict__ gx,
                        const float* __restrict__ bx, float* __restrict__ out) {
    __shared__ float p[256];
    int t = threadIdx.x;
    p[t] = colsum[t] * (1.0f / (float)NODES);
    __syncthreads();
    if (t < 64) {
        float acc = bf[t];
        for (int c = 0; c < 256; c++) acc = fmaf(p[c], Wf[c * 64 + t], acc);
        float sum = acc;
        for (int o = 32; o > 0; o >>= 1) sum += __shfl_xor(sum, o);
        float mu = sum * (1.0f / 64.0f);
        float d = acc - mu;
        float vs = d * d;
        for (int o = 32; o > 0; o >>= 1) vs += __shfl_xor(vs, o);
        float var = vs * (1.0f / 64.0f);
        float y = d * rsqrtf(var + EPSV) * gx[t] + bx[t];
        out[t] = fmaxf(y, 0.f);
    }
}

extern "C" void kernel_launch(void* const* d_in, const int* in_sizes, int n_in,
                              void* d_out, int out_size, void* d_ws, size_t ws_size,
                              hipStream_t stream) {
    const float* x   = (const float*)d_in[0];
    const int*   ei  = (const int*)d_in[1];
    const float* t1  = (const float*)d_in[2];
    const float* Wl1 = (const float*)d_in[3];
    const float* bl1 = (const float*)d_in[4];
    const float* Wr1 = (const float*)d_in[5];
    const float* g1  = (const float*)d_in[6];
    const float* be1 = (const float*)d_in[7];
    const float* t2  = (const float*)d_in[8];
    const float* Wl2 = (const float*)d_in[9];
    const float* bl2 = (const float*)d_in[10];
    const float* Wr2 = (const float*)d_in[11];
    const float* g2  = (const float*)d_in[12];
    const float* be2 = (const float*)d_in[13];
    const float* Wf  = (const float*)d_in[14];
    const float* bf  = (const float*)d_in[15];
    const float* gx  = (const float*)d_in[16];
    const float* bx  = (const float*)d_in[17];
    float* out = (float*)d_out;

    char* ws = (char*)d_ws;
    size_t off = 0;
    auto alloc = [&](size_t bytes) { size_t o = off; off = (off + bytes + 511) & ~511ull; return o; };
    size_t o_counts = alloc((size_t)NODES * 4);
    size_t o_cursor = alloc((size_t)NODES * 4);
    size_t o_acc    = alloc(4 * 4);
    size_t o_colsum = alloc(256 * 4);
    size_t zero_bytes = off;
    size_t o_offs = alloc((size_t)(NODES + 1) * 4);
    size_t o_csrc = alloc((size_t)EDGES * 4);
    size_t o_w1l  = alloc((size_t)512 * 256 * 2);
    size_t o_w1r  = alloc((size_t)512 * 256 * 2);
    size_t o_w2l  = alloc((size_t)256 * 512 * 2);
    size_t o_w2r  = alloc((size_t)256 * 512 * 2);
    size_t o_bufX = alloc((size_t)NODES * 256 * 2);  // xb, later h2_pre (bf16)
    size_t o_agg  = alloc((size_t)NODES * 512 * 2);  // agg1b / agg2b
    size_t o_h1   = alloc((size_t)NODES * 512 * 2);  // h1 pre-LN bf16, LN'd in place

    int*   counts = (int*)(ws + o_counts);
    int*   cursor = (int*)(ws + o_cursor);
    float* acc    = (float*)(ws + o_acc);      // [0,1]=L1 stats, [2,3]=L2 stats
    float* colsum = (float*)(ws + o_colsum);
    int*   offs   = (int*)(ws + o_offs);
    int*   csrc   = (int*)(ws + o_csrc);
    unsigned short* w1lt = (unsigned short*)(ws + o_w1l);
    unsigned short* w1rt = (unsigned short*)(ws + o_w1r);
    unsigned short* w2lt = (unsigned short*)(ws + o_w2l);
    unsigned short* w2rt = (unsigned short*)(ws + o_w2r);
    unsigned short* xb   = (unsigned short*)(ws + o_bufX);
    unsigned short* h2p  = (unsigned short*)(ws + o_bufX);  // reuse after xb dead
    unsigned short* aggb = (unsigned short*)(ws + o_agg);
    unsigned short* h1   = (unsigned short*)(ws + o_h1);

    const int* src = ei;
    const int* dst = ei + EDGES;

    hipMemsetAsync(ws, 0, zero_bytes, stream);

    // CSR + precasts
    k_count<<<(EDGES + 255) / 256, 256, 0, stream>>>(dst, counts);
    k_scan<<<1, 256, 0, stream>>>(counts, offs);
    k_scatter<<<(EDGES + 255) / 256, 256, 0, stream>>>(src, dst, offs, cursor, csrc);
    k_cast<<<NODES * 256 / 4 / 256, 256, 0, stream>>>(x, xb);
    k_transpose_all<<<dim3(128, 1, 4), dim3(32, 8), 0, stream>>>(
        Wl1, Wr1, Wl2, Wr2, w1lt, w1rt, w2lt, w2rt);

    // ----- layer 1 -----
    k_agg<256><<<(NODES + 3) / 4, 256, 0, stream>>>(xb, t1, offs, csrc, aggb);
    k_gemm_mfma<256, 512><<<dim3((NODES + 127) / 128, 4), 256, 0, stream>>>(
        aggb, w1lt, xb, w1rt, bl1, h1, NODES, acc);
    k_ln_relu_b<512><<<NODES * 512 / 8 / 256, 256, 0, stream>>>(h1, NODES * 512, acc, g1, be1);

    // ----- layer 2 -----
    k_agg<512><<<(NODES + 3) / 4, 256, 0, stream>>>(h1, t2, offs, csrc, aggb);
    k_gemm_mfma<512, 256><<<dim3((NODES + 127) / 128, 2), 256, 0, stream>>>(
        aggb, w2lt, h1, w2rt, bl2, h2p, NODES, acc + 2);
    k_ln_colsum<<<1024, 256, 0, stream>>>(h2p, NODES * 256, acc + 2, g2, be2, colsum);

    // ----- head -----
    k_final<<<1, 256, 0, stream>>>(colsum, Wf, bf, gx, bx, out);
}

// Round 4
// 359.311 us; speedup vs baseline: 2.1119x; 1.0357x over previous
//
#include <hip/hip_runtime.h>
#include <math.h>

#define NODES 20000
#define MPAD  20096          // NODES padded to multiple of 128 (GEMM M-tiles)
#define EDGES 320000
#define EPSV  1e-5f
#define LOG2E 1.4426950408889634f

typedef short bf16x8 __attribute__((ext_vector_type(8)));
typedef float f32x4  __attribute__((ext_vector_type(4)));
typedef float f2     __attribute__((ext_vector_type(2)));

__device__ __forceinline__ unsigned short f2bf(float f) {
    unsigned int u = __float_as_uint(f);
    u = (u + 0x7fffu + ((u >> 16) & 1u)) >> 16;
    return (unsigned short)u;
}
__device__ __forceinline__ float bf2f(unsigned short h) {
    return __uint_as_float(((unsigned int)h) << 16);
}

// async global->LDS, 16B per lane; lds dest = wave-uniform base + lane*16
__device__ __forceinline__ void load_lds16(const unsigned short* g, unsigned short* l) {
    __builtin_amdgcn_global_load_lds(
        (const __attribute__((address_space(1))) unsigned int*)g,
        (__attribute__((address_space(3))) unsigned int*)l, 16, 0, 0);
}

// ---------------- CSR build ----------------
__global__ void k_count(const int* __restrict__ dst, int* __restrict__ counts) {
    int e = blockIdx.x * blockDim.x + threadIdx.x;
    if (e < EDGES) atomicAdd(&counts[dst[e]], 1);
}

__global__ void k_scan(const int* __restrict__ counts, int* __restrict__ offs) {
    __shared__ int ssum[256];
    int t = threadIdx.x;
    const int chunk = (NODES + 255) / 256;
    int b = t * chunk, e = b + chunk;
    if (b > NODES) b = NODES;
    if (e > NODES) e = NODES;
    int s = 0;
    for (int i = b; i < e; i++) s += counts[i];
    ssum[t] = s;
    __syncthreads();
    if (t == 0) {
        int run = 0;
        for (int i = 0; i < 256; i++) { int v = ssum[i]; ssum[i] = run; run += v; }
        offs[NODES] = run;
    }
    __syncthreads();
    int run = ssum[t];
    for (int i = b; i < e; i++) { offs[i] = run; run += counts[i]; }
}

__global__ void k_scatter(const int* __restrict__ src, const int* __restrict__ dst,
                          const int* __restrict__ offs, int* __restrict__ cursor,
                          int* __restrict__ csr_src) {
    int e = blockIdx.x * blockDim.x + threadIdx.x;
    if (e < EDGES) {
        int d = dst[e];
        int pos = atomicAdd(&cursor[d], 1);
        csr_src[offs[d] + pos] = src[e];
    }
}

// ---------------- prep: fp32 -> bf16 cast ----------------
__global__ void k_cast(const float* __restrict__ in, unsigned short* __restrict__ out) {
    int i = (blockIdx.x * blockDim.x + threadIdx.x) * 4;
    float4 v = *(const float4*)(in + i);
    out[i + 0] = f2bf(v.x); out[i + 1] = f2bf(v.y);
    out[i + 2] = f2bf(v.z); out[i + 3] = f2bf(v.w);
}

// ------- prep: all four W [K][N] fp32 -> Wt [N][K] bf16, one dispatch --------
__global__ void k_transpose_all(const float* __restrict__ Wl1, const float* __restrict__ Wr1,
                                const float* __restrict__ Wl2, const float* __restrict__ Wr2,
                                unsigned short* __restrict__ o1l, unsigned short* __restrict__ o1r,
                                unsigned short* __restrict__ o2l, unsigned short* __restrict__ o2r) {
    __shared__ float tile[32][33];
    int z = blockIdx.z;
    const float* W = (z == 0) ? Wl1 : (z == 1) ? Wr1 : (z == 2) ? Wl2 : Wr2;
    unsigned short* Wt = (z == 0) ? o1l : (z == 1) ? o1r : (z == 2) ? o2l : o2r;
    int K = (z < 2) ? 256 : 512, N = (z < 2) ? 512 : 256;
    int nb = N / 32;
    int n0 = (blockIdx.x % nb) * 32, k0 = (blockIdx.x / nb) * 32;
    int tx = threadIdx.x, ty = threadIdx.y;   // blockDim (32,8)
#pragma unroll
    for (int j = 0; j < 4; j++)
        tile[ty + j * 8][tx] = W[(size_t)(k0 + ty + j * 8) * N + n0 + tx];
    __syncthreads();
#pragma unroll
    for (int j = 0; j < 4; j++)
        Wt[(size_t)(n0 + ty + j * 8) * K + k0 + tx] = f2bf(tile[tx][ty + j * 8]);
}

// ------- per-channel softmax aggregation, un-stabilized (inputs bounded) -----
// one wave per node; lane holds C/64 contiguous channels; packed-f32 math.
template <int C, int UNR>
__global__ void k_agg(const unsigned short* __restrict__ xb, const float* __restrict__ tt,
                      const int* __restrict__ offs, const int* __restrict__ csr,
                      unsigned short* __restrict__ out) {
    constexpr int VPL = C / 64;          // bf16 per lane
    constexpr int W = VPL / 2;           // dwords per lane
    typedef unsigned int uv __attribute__((ext_vector_type(W)));
    typedef unsigned short usv __attribute__((ext_vector_type(VPL)));
    int wave = (int)((blockIdx.x * (unsigned)blockDim.x + threadIdx.x) >> 6);
    int lane = threadIdx.x & 63;
    if (wave >= NODES) return;
    int beg = offs[wave], end = offs[wave + 1];
    int cb = lane * VPL;
    f2 tl[W], l[W], s[W];
#pragma unroll
    for (int i = 0; i < W; i++) {
        tl[i][0] = tt[cb + 2 * i] * LOG2E;
        tl[i][1] = tt[cb + 2 * i + 1] * LOG2E;
        l[i][0] = 0.f; l[i][1] = 0.f;
        s[i][0] = 0.f; s[i][1] = 0.f;
    }
    int k = beg;
    for (; k + UNR <= end; k += UNR) {
        uv v[UNR];
#pragma unroll
        for (int u = 0; u < UNR; u++) {
            int sn = csr[k + u];
            v[u] = *(const uv*)(xb + (size_t)sn * C + cb);
        }
#pragma unroll
        for (int u = 0; u < UNR; u++)
#pragma unroll
            for (int i = 0; i < W; i++) {
                unsigned wd = v[u][i];
                f2 xv;
                xv[0] = __uint_as_float(wd << 16);
                xv[1] = __uint_as_float(wd & 0xffff0000u);
                f2 a = xv * tl[i];
                f2 p;
                p[0] = __builtin_amdgcn_exp2f(a[0]);
                p[1] = __builtin_amdgcn_exp2f(a[1]);
                l[i] += p;
                s[i] = __builtin_elementwise_fma(p, xv, s[i]);
            }
    }
    for (; k < end; k++) {
        int sn = csr[k];
        uv vv = *(const uv*)(xb + (size_t)sn * C + cb);
#pragma unroll
        for (int i = 0; i < W; i++) {
            unsigned wd = vv[i];
            f2 xv;
            xv[0] = __uint_as_float(wd << 16);
            xv[1] = __uint_as_float(wd & 0xffff0000u);
            f2 a = xv * tl[i];
            f2 p;
            p[0] = __builtin_amdgcn_exp2f(a[0]);
            p[1] = __builtin_amdgcn_exp2f(a[1]);
            l[i] += p;
            s[i] = __builtin_elementwise_fma(p, xv, s[i]);
        }
    }
    bool has = end > beg;
    usv o;
#pragma unroll
    for (int i = 0; i < W; i++) {
        o[2 * i]     = f2bf(has ? s[i][0] / l[i][0] : 0.f);
        o[2 * i + 1] = f2bf(has ? s[i][1] / l[i][1] : 0.f);
    }
    *(usv*)(out + (size_t)wave * C + cb) = o;
}

// ---------------- dual bf16 MFMA GEMM: C = A1*B1t^T + A2*B2t^T + bias ---------
// 128x128 tile, BK=32, 4 waves (2x2), 4x4 mfma_16x16x32 per wave.
// Staging via global_load_lds width=16 (no bounds checks: A buffers padded to
// MPAD rows; garbage pad rows only affect discarded C rows). B pre-transposed
// bf16 [N][K]. Output bf16; LN sum/sumsq fused via 2 atomics/block.
template <int K, int NT>
__global__ __launch_bounds__(256) void k_gemm_mfma(
    const unsigned short* __restrict__ A1, const unsigned short* __restrict__ B1t,
    const unsigned short* __restrict__ A2, const unsigned short* __restrict__ B2t,
    const float* __restrict__ bias, unsigned short* __restrict__ Co, int M,
    float* __restrict__ stat) {
    __shared__ short As[128 * 32];   // unpadded: global_load_lds needs contiguity
    __shared__ short Bs[128 * 32];
    __shared__ float rs[256], rq[256];

    int t = threadIdx.x;
    int m0 = blockIdx.x * 128, n0 = blockIdx.y * 128;
    int wv = t >> 6, lane = t & 63;
    int wm = wv & 1, wn = wv >> 1;
    int lm = lane & 15, quad = lane >> 4;
    int sr = t >> 2;             // staging row 0..63 (+64 on it=1)
    int sc8 = (t & 3) * 8;       // staging k-offset in shorts {0,8,16,24}

    f32x4 acc[4][4] = {};

    for (int ph = 0; ph < 2; ph++) {
        const unsigned short* __restrict__ A  = ph ? A2 : A1;
        const unsigned short* __restrict__ Bt = ph ? B2t : B1t;
        for (int k0 = 0; k0 < K; k0 += 32) {
#pragma unroll
            for (int it = 0; it < 2; it++) {
                load_lds16(A  + (size_t)(m0 + it * 64 + sr) * K + k0 + sc8,
                           (unsigned short*)&As[it * 2048 + wv * 512]);
                load_lds16(Bt + (size_t)(n0 + it * 64 + sr) * K + k0 + sc8,
                           (unsigned short*)&Bs[it * 2048 + wv * 512]);
            }
            __syncthreads();
            bf16x8 af[4], bfr[4];
#pragma unroll
            for (int i = 0; i < 4; i++) {
                af[i]  = *(const bf16x8*)&As[(wm * 64 + i * 16 + lm) * 32 + quad * 8];
                bfr[i] = *(const bf16x8*)&Bs[(wn * 64 + i * 16 + lm) * 32 + quad * 8];
            }
#pragma unroll
            for (int mi = 0; mi < 4; mi++)
#pragma unroll
                for (int nj = 0; nj < 4; nj++)
                    acc[mi][nj] = __builtin_amdgcn_mfma_f32_16x16x32_bf16(
                        af[mi], bfr[nj], acc[mi][nj], 0, 0, 0);
            __syncthreads();
        }
    }

    // epilogue: +bias, store bf16, fused LN sum/sumsq (rows < M only)
    float sum = 0.f, ss = 0.f;
#pragma unroll
    for (int mi = 0; mi < 4; mi++) {
        int rb = m0 + wm * 64 + mi * 16 + quad * 4;
#pragma unroll
        for (int nj = 0; nj < 4; nj++) {
            int col = n0 + wn * 64 + nj * 16 + lm;
            float bb = bias[col];
#pragma unroll
            for (int rg = 0; rg < 4; rg++) {
                int row = rb + rg;
                if (row < M) {
                    float y = acc[mi][nj][rg] + bb;
                    Co[(size_t)row * NT + col] = f2bf(y);
                    sum += y; ss += y * y;
                }
            }
        }
    }
    rs[t] = sum; rq[t] = ss;
    __syncthreads();
    for (int o = 128; o > 0; o >>= 1) {
        if (t < o) { rs[t] += rs[t + o]; rq[t] += rq[t + o]; }
        __syncthreads();
    }
    if (t == 0) { atomicAdd(&stat[0], rs[0]); atomicAdd(&stat[1], rq[0]); }
}

// ---------------- graph-LN + ReLU, in-place bf16, vectorized x8 --------------
template <int C>
__global__ void k_ln_relu_b(unsigned short* __restrict__ h, int n,
                            const float* __restrict__ st,
                            const float* __restrict__ g, const float* __restrict__ b) {
    typedef unsigned short us8 __attribute__((ext_vector_type(8)));
    float mu = st[0] / (float)n;
    float var = st[1] / (float)n - mu * mu;
    var = var < 0.f ? 0.f : var;
    float inv = 1.0f / (sqrtf(var) + EPSV);
    int i8 = (blockIdx.x * blockDim.x + threadIdx.x) * 8;
    if (i8 >= n) return;
    int c = i8 & (C - 1);
    us8 v = *(const us8*)(h + i8);
    us8 o;
#pragma unroll
    for (int j = 0; j < 8; j++) {
        float y = (bf2f(v[j]) - mu) * inv * g[c + j] + b[c + j];
        o[j] = f2bf(fmaxf(y, 0.f));
    }
    *(us8*)(h + i8) = o;
}

// graph-LN + ReLU + column-sum only (layer 2; h2 not needed afterwards)
__global__ void k_ln_colsum(const unsigned short* __restrict__ h, int n,
                            const float* __restrict__ st,
                            const float* __restrict__ g, const float* __restrict__ b,
                            float* __restrict__ colsum) {
    float mu = st[0] / (float)n;
    float var = st[1] / (float)n - mu * mu;
    var = var < 0.f ? 0.f : var;
    float inv = 1.0f / (sqrtf(var) + EPSV);
    int t = threadIdx.x;
    float gv = g[t], bv = b[t];
    float local = 0.f;
    int stride = gridDim.x * blockDim.x;   // multiple of 256 -> channel == t always
    for (int i = blockIdx.x * blockDim.x + t; i < n; i += stride) {
        float y = (bf2f(h[i]) - mu) * inv * gv + bv;
        local += fmaxf(y, 0.f);
    }
    atomicAdd(&colsum[t], local);
}

// ---------------- head: mean-pool @ Wf + bf -> LN(64) -> relu ----------------
__global__ void k_final(const float* __restrict__ colsum, const float* __restrict__ Wf,
                        const float* __restrict__ bf, const float* __restrict__ gx,
                        const float* __restrict__ bx, float* __restrict__ out) {
    __shared__ float p[256];
    int t = threadIdx.x;
    p[t] = colsum[t] * (1.0f / (float)NODES);
    __syncthreads();
    if (t < 64) {
        float acc = bf[t];
        for (int c = 0; c < 256; c++) acc = fmaf(p[c], Wf[c * 64 + t], acc);
        float sum = acc;
        for (int o = 32; o > 0; o >>= 1) sum += __shfl_xor(sum, o);
        float mu = sum * (1.0f / 64.0f);
        float d = acc - mu;
        float vs = d * d;
        for (int o = 32; o > 0; o >>= 1) vs += __shfl_xor(vs, o);
        float var = vs * (1.0f / 64.0f);
        float y = d * rsqrtf(var + EPSV) * gx[t] + bx[t];
        out[t] = fmaxf(y, 0.f);
    }
}

extern "C" void kernel_launch(void* const* d_in, const int* in_sizes, int n_in,
                              void* d_out, int out_size, void* d_ws, size_t ws_size,
                              hipStream_t stream) {
    const float* x   = (const float*)d_in[0];
    const int*   ei  = (const int*)d_in[1];
    const float* t1  = (const float*)d_in[2];
    const float* Wl1 = (const float*)d_in[3];
    const float* bl1 = (const float*)d_in[4];
    const float* Wr1 = (const float*)d_in[5];
    const float* g1  = (const float*)d_in[6];
    const float* be1 = (const float*)d_in[7];
    const float* t2  = (const float*)d_in[8];
    const float* Wl2 = (const float*)d_in[9];
    const float* bl2 = (const float*)d_in[10];
    const float* Wr2 = (const float*)d_in[11];
    const float* g2  = (const float*)d_in[12];
    const float* be2 = (const float*)d_in[13];
    const float* Wf  = (const float*)d_in[14];
    const float* bf  = (const float*)d_in[15];
    const float* gx  = (const float*)d_in[16];
    const float* bx  = (const float*)d_in[17];
    float* out = (float*)d_out;

    char* ws = (char*)d_ws;
    size_t off = 0;
    auto alloc = [&](size_t bytes) { size_t o = off; off = (off + bytes + 511) & ~511ull; return o; };
    size_t o_counts = alloc((size_t)NODES * 4);
    size_t o_cursor = alloc((size_t)NODES * 4);
    size_t o_acc    = alloc(4 * 4);
    size_t o_colsum = alloc(256 * 4);
    size_t zero_bytes = off;
    size_t o_offs = alloc((size_t)(NODES + 1) * 4);
    size_t o_csrc = alloc((size_t)EDGES * 4);
    size_t o_w1l  = alloc((size_t)512 * 256 * 2);
    size_t o_w1r  = alloc((size_t)512 * 256 * 2);
    size_t o_w2l  = alloc((size_t)256 * 512 * 2);
    size_t o_w2r  = alloc((size_t)256 * 512 * 2);
    size_t o_bufX = alloc((size_t)MPAD * 256 * 2);   // xb, later h2_pre (bf16)
    size_t o_agg  = alloc((size_t)MPAD * 512 * 2);   // agg1b / agg2b
    size_t o_h1   = alloc((size_t)MPAD * 512 * 2);   // h1 pre-LN bf16, LN'd in place

    int*   counts = (int*)(ws + o_counts);
    int*   cursor = (int*)(ws + o_cursor);
    float* acc    = (float*)(ws + o_acc);      // [0,1]=L1 stats, [2,3]=L2 stats
    float* colsum = (float*)(ws + o_colsum);
    int*   offs   = (int*)(ws + o_offs);
    int*   csrc   = (int*)(ws + o_csrc);
    unsigned short* w1lt = (unsigned short*)(ws + o_w1l);
    unsigned short* w1rt = (unsigned short*)(ws + o_w1r);
    unsigned short* w2lt = (unsigned short*)(ws + o_w2l);
    unsigned short* w2rt = (unsigned short*)(ws + o_w2r);
    unsigned short* xb   = (unsigned short*)(ws + o_bufX);
    unsigned short* h2p  = (unsigned short*)(ws + o_bufX);  // reuse after xb dead
    unsigned short* aggb = (unsigned short*)(ws + o_agg);
    unsigned short* h1   = (unsigned short*)(ws + o_h1);

    const int* src = ei;
    const int* dst = ei + EDGES;

    hipMemsetAsync(ws, 0, zero_bytes, stream);

    // CSR + precasts
    k_count<<<(EDGES + 255) / 256, 256, 0, stream>>>(dst, counts);
    k_scan<<<1, 256, 0, stream>>>(counts, offs);
    k_scatter<<<(EDGES + 255) / 256, 256, 0, stream>>>(src, dst, offs, cursor, csrc);
    k_cast<<<NODES * 256 / 4 / 256, 256, 0, stream>>>(x, xb);
    k_transpose_all<<<dim3(128, 1, 4), dim3(32, 8), 0, stream>>>(
        Wl1, Wr1, Wl2, Wr2, w1lt, w1rt, w2lt, w2rt);

    // ----- layer 1 -----
    k_agg<256, 4><<<(NODES + 3) / 4, 256, 0, stream>>>(xb, t1, offs, csrc, aggb);
    k_gemm_mfma<256, 512><<<dim3(MPAD / 128, 4), 256, 0, stream>>>(
        aggb, w1lt, xb, w1rt, bl1, h1, NODES, acc);
    k_ln_relu_b<512><<<NODES * 512 / 8 / 256, 256, 0, stream>>>(h1, NODES * 512, acc, g1, be1);

    // ----- layer 2 -----
    k_agg<512, 2><<<(NODES + 3) / 4, 256, 0, stream>>>(h1, t2, offs, csrc, aggb);
    k_gemm_mfma<512, 256><<<dim3(MPAD / 128, 2), 256, 0, stream>>>(
        aggb, w2lt, h1, w2rt, bl2, h2p, NODES, acc + 2);
    k_ln_colsum<<<1024, 256, 0, stream>>>(h2p, NODES * 256, acc + 2, g2, be2, colsum);

    // ----- head -----
    k_final<<<1, 256, 0, stream>>>(colsum, Wf, bf, gx, bx, out);
}

// Round 5
// 353.508 us; speedup vs baseline: 2.1466x; 1.0164x over previous
//
#include <hip/hip_runtime.h>
#include <math.h>

#define NODES 20000
#define MPAD  20096          // NODES padded to multiple of 128 (GEMM M-tiles)
#define EDGES 320000
#define EPSV  1e-5f
#define LOG2E 1.4426950408889634f

typedef short bf16x8 __attribute__((ext_vector_type(8)));
typedef float f32x4  __attribute__((ext_vector_type(4)));
typedef float f2     __attribute__((ext_vector_type(2)));

__device__ __forceinline__ unsigned short f2bf(float f) {
    unsigned int u = __float_as_uint(f);
    u = (u + 0x7fffu + ((u >> 16) & 1u)) >> 16;
    return (unsigned short)u;
}
__device__ __forceinline__ float bf2f(unsigned short h) {
    return __uint_as_float(((unsigned int)h) << 16);
}

// async global->LDS, 16B per lane; lds dest = wave-uniform base + lane*16
__device__ __forceinline__ void load_lds16(const unsigned short* g, unsigned short* l) {
    __builtin_amdgcn_global_load_lds(
        (const __attribute__((address_space(1))) unsigned int*)g,
        (__attribute__((address_space(3))) unsigned int*)l, 16, 0, 0);
}

// ---------------- CSR build ----------------
__global__ void k_count(const int* __restrict__ dst, int* __restrict__ counts) {
    int e = blockIdx.x * blockDim.x + threadIdx.x;
    if (e < EDGES) atomicAdd(&counts[dst[e]], 1);
}

__global__ void k_scan(const int* __restrict__ counts, int* __restrict__ offs) {
    __shared__ int ssum[256];
    int t = threadIdx.x;
    const int chunk = (NODES + 255) / 256;
    int b = t * chunk, e = b + chunk;
    if (b > NODES) b = NODES;
    if (e > NODES) e = NODES;
    int s = 0;
    for (int i = b; i < e; i++) s += counts[i];
    // Hillis-Steele inclusive scan over 256 chunk sums
    ssum[t] = s;
    __syncthreads();
    int v = s;
#pragma unroll
    for (int o = 1; o < 256; o <<= 1) {
        int add = (t >= o) ? ssum[t - o] : 0;
        __syncthreads();
        v += add;
        ssum[t] = v;
        __syncthreads();
    }
    int run = v - s;          // exclusive prefix of this chunk
    if (t == 255) offs[NODES] = v;
    for (int i = b; i < e; i++) { offs[i] = run; run += counts[i]; }
}

__global__ void k_scatter(const int* __restrict__ src, const int* __restrict__ dst,
                          const int* __restrict__ offs, int* __restrict__ cursor,
                          int* __restrict__ csr_src) {
    int e = blockIdx.x * blockDim.x + threadIdx.x;
    if (e < EDGES) {
        int d = dst[e];
        int pos = atomicAdd(&cursor[d], 1);
        csr_src[offs[d] + pos] = src[e];
    }
}

// ---------------- prep: fp32 -> bf16 cast ----------------
__global__ void k_cast(const float* __restrict__ in, unsigned short* __restrict__ out) {
    int i = (blockIdx.x * blockDim.x + threadIdx.x) * 4;
    float4 v = *(const float4*)(in + i);
    out[i + 0] = f2bf(v.x); out[i + 1] = f2bf(v.y);
    out[i + 2] = f2bf(v.z); out[i + 3] = f2bf(v.w);
}

// ------- prep: all four W [K][N] fp32 -> Wt [N][K] bf16, one dispatch --------
__global__ void k_transpose_all(const float* __restrict__ Wl1, const float* __restrict__ Wr1,
                                const float* __restrict__ Wl2, const float* __restrict__ Wr2,
                                unsigned short* __restrict__ o1l, unsigned short* __restrict__ o1r,
                                unsigned short* __restrict__ o2l, unsigned short* __restrict__ o2r) {
    __shared__ float tile[32][33];
    int z = blockIdx.z;
    const float* W = (z == 0) ? Wl1 : (z == 1) ? Wr1 : (z == 2) ? Wl2 : Wr2;
    unsigned short* Wt = (z == 0) ? o1l : (z == 1) ? o1r : (z == 2) ? o2l : o2r;
    int K = (z < 2) ? 256 : 512, N = (z < 2) ? 512 : 256;
    int nb = N / 32;
    int n0 = (blockIdx.x % nb) * 32, k0 = (blockIdx.x / nb) * 32;
    int tx = threadIdx.x, ty = threadIdx.y;   // blockDim (32,8)
#pragma unroll
    for (int j = 0; j < 4; j++)
        tile[ty + j * 8][tx] = W[(size_t)(k0 + ty + j * 8) * N + n0 + tx];
    __syncthreads();
#pragma unroll
    for (int j = 0; j < 4; j++)
        Wt[(size_t)(n0 + ty + j * 8) * K + k0 + tx] = f2bf(tile[tx][ty + j * 8]);
}

// ------- per-channel softmax aggregation, un-stabilized (inputs bounded) -----
// one wave per node. Wave-uniform CSR walk: readfirstlane forces beg/end/k into
// SGPRs -> csr[k] becomes s_load, row base math goes scalar, vector pipe only
// does the gather (loop-invariant per-lane offset) + packed-f32 math.
template <int C, int UNR>
__global__ void k_agg(const unsigned short* __restrict__ xb, const float* __restrict__ tt,
                      const int* __restrict__ offs, const int* __restrict__ csr,
                      unsigned short* __restrict__ out) {
    constexpr int VPL = C / 64;          // bf16 per lane
    constexpr int W = VPL / 2;           // dwords per lane
    typedef unsigned int uv __attribute__((ext_vector_type(W)));
    typedef unsigned short usv __attribute__((ext_vector_type(VPL)));
    int wave = (int)((blockIdx.x * (unsigned)blockDim.x + threadIdx.x) >> 6);
    int lane = threadIdx.x & 63;
    if (wave >= NODES) return;
    int beg = __builtin_amdgcn_readfirstlane(offs[wave]);
    int end = __builtin_amdgcn_readfirstlane(offs[wave + 1]);
    int cb = lane * VPL;
    const unsigned short* __restrict__ xcb = xb + cb;   // per-lane, loop-invariant
    f2 tl[W], l[W], s[W];
#pragma unroll
    for (int i = 0; i < W; i++) {
        tl[i][0] = tt[cb + 2 * i] * LOG2E;
        tl[i][1] = tt[cb + 2 * i + 1] * LOG2E;
        l[i][0] = 0.f; l[i][1] = 0.f;
        s[i][0] = 0.f; s[i][1] = 0.f;
    }
    int k = beg;
    for (; k + UNR <= end; k += UNR) {
        uv v[UNR];
#pragma unroll
        for (int u = 0; u < UNR; u++) {
            int sn = csr[k + u];                     // uniform -> s_load
            v[u] = *(const uv*)(xcb + (size_t)sn * C);
        }
#pragma unroll
        for (int u = 0; u < UNR; u++)
#pragma unroll
            for (int i = 0; i < W; i++) {
                unsigned wd = v[u][i];
                f2 xv;
                xv[0] = __uint_as_float(wd << 16);
                xv[1] = __uint_as_float(wd & 0xffff0000u);
                f2 a = xv * tl[i];
                f2 p;
                p[0] = __builtin_amdgcn_exp2f(a[0]);
                p[1] = __builtin_amdgcn_exp2f(a[1]);
                l[i] += p;
                s[i] = __builtin_elementwise_fma(p, xv, s[i]);
            }
    }
    for (; k < end; k++) {
        int sn = csr[k];
        uv vv = *(const uv*)(xcb + (size_t)sn * C);
#pragma unroll
        for (int i = 0; i < W; i++) {
            unsigned wd = vv[i];
            f2 xv;
            xv[0] = __uint_as_float(wd << 16);
            xv[1] = __uint_as_float(wd & 0xffff0000u);
            f2 a = xv * tl[i];
            f2 p;
            p[0] = __builtin_amdgcn_exp2f(a[0]);
            p[1] = __builtin_amdgcn_exp2f(a[1]);
            l[i] += p;
            s[i] = __builtin_elementwise_fma(p, xv, s[i]);
        }
    }
    bool has = end > beg;
    usv o;
#pragma unroll
    for (int i = 0; i < W; i++) {
        o[2 * i]     = f2bf(has ? s[i][0] / l[i][0] : 0.f);
        o[2 * i + 1] = f2bf(has ? s[i][1] / l[i][1] : 0.f);
    }
    *(usv*)(out + (size_t)wave * C + cb) = o;
}

// ---------------- dual bf16 MFMA GEMM: C = A1*B1t^T + A2*B2t^T + bias ---------
// 128x128 tile, BK=32, 4 waves (2x2), 4x4 mfma_16x16x32 per wave.
// Staging via global_load_lds width=16 (no bounds checks: A buffers padded to
// MPAD rows; garbage pad rows only affect discarded C rows). B pre-transposed
// bf16 [N][K]. Output bf16; LN sum/sumsq fused via 2 atomics/block.
template <int K, int NT>
__global__ __launch_bounds__(256) void k_gemm_mfma(
    const unsigned short* __restrict__ A1, const unsigned short* __restrict__ B1t,
    const unsigned short* __restrict__ A2, const unsigned short* __restrict__ B2t,
    const float* __restrict__ bias, unsigned short* __restrict__ Co, int M,
    float* __restrict__ stat) {
    __shared__ short As[128 * 32];   // unpadded: global_load_lds needs contiguity
    __shared__ short Bs[128 * 32];
    __shared__ float rs[256], rq[256];

    int t = threadIdx.x;
    int m0 = blockIdx.x * 128, n0 = blockIdx.y * 128;
    int wv = t >> 6, lane = t & 63;
    int wm = wv & 1, wn = wv >> 1;
    int lm = lane & 15, quad = lane >> 4;
    int sr = t >> 2;             // staging row 0..63 (+64 on it=1)
    int sc8 = (t & 3) * 8;       // staging k-offset in shorts {0,8,16,24}

    f32x4 acc[4][4] = {};

    for (int ph = 0; ph < 2; ph++) {
        const unsigned short* __restrict__ A  = ph ? A2 : A1;
        const unsigned short* __restrict__ Bt = ph ? B2t : B1t;
        for (int k0 = 0; k0 < K; k0 += 32) {
#pragma unroll
            for (int it = 0; it < 2; it++) {
                load_lds16(A  + (size_t)(m0 + it * 64 + sr) * K + k0 + sc8,
                           (unsigned short*)&As[it * 2048 + wv * 512]);
                load_lds16(Bt + (size_t)(n0 + it * 64 + sr) * K + k0 + sc8,
                           (unsigned short*)&Bs[it * 2048 + wv * 512]);
            }
            __syncthreads();
            bf16x8 af[4], bfr[4];
#pragma unroll
            for (int i = 0; i < 4; i++) {
                af[i]  = *(const bf16x8*)&As[(wm * 64 + i * 16 + lm) * 32 + quad * 8];
                bfr[i] = *(const bf16x8*)&Bs[(wn * 64 + i * 16 + lm) * 32 + quad * 8];
            }
#pragma unroll
            for (int mi = 0; mi < 4; mi++)
#pragma unroll
                for (int nj = 0; nj < 4; nj++)
                    acc[mi][nj] = __builtin_amdgcn_mfma_f32_16x16x32_bf16(
                        af[mi], bfr[nj], acc[mi][nj], 0, 0, 0);
            __syncthreads();
        }
    }

    // epilogue: +bias, store bf16, fused LN sum/sumsq (rows < M only)
    float sum = 0.f, ss = 0.f;
#pragma unroll
    for (int mi = 0; mi < 4; mi++) {
        int rb = m0 + wm * 64 + mi * 16 + quad * 4;
#pragma unroll
        for (int nj = 0; nj < 4; nj++) {
            int col = n0 + wn * 64 + nj * 16 + lm;
            float bb = bias[col];
#pragma unroll
            for (int rg = 0; rg < 4; rg++) {
                int row = rb + rg;
                if (row < M) {
                    float y = acc[mi][nj][rg] + bb;
                    Co[(size_t)row * NT + col] = f2bf(y);
                    sum += y; ss += y * y;
                }
            }
        }
    }
    rs[t] = sum; rq[t] = ss;
    __syncthreads();
    for (int o = 128; o > 0; o >>= 1) {
        if (t < o) { rs[t] += rs[t + o]; rq[t] += rq[t + o]; }
        __syncthreads();
    }
    if (t == 0) { atomicAdd(&stat[0], rs[0]); atomicAdd(&stat[1], rq[0]); }
}

// ---------------- graph-LN + ReLU, in-place bf16, vectorized x8 --------------
template <int C>
__global__ void k_ln_relu_b(unsigned short* __restrict__ h, int n,
                            const float* __restrict__ st,
                            const float* __restrict__ g, const float* __restrict__ b) {
    typedef unsigned short us8 __attribute__((ext_vector_type(8)));
    float mu = st[0] / (float)n;
    float var = st[1] / (float)n - mu * mu;
    var = var < 0.f ? 0.f : var;
    float inv = 1.0f / (sqrtf(var) + EPSV);
    int i8 = (blockIdx.x * blockDim.x + threadIdx.x) * 8;
    if (i8 >= n) return;
    int c = i8 & (C - 1);
    us8 v = *(const us8*)(h + i8);
    us8 o;
#pragma unroll
    for (int j = 0; j < 8; j++) {
        float y = (bf2f(v[j]) - mu) * inv * g[c + j] + b[c + j];
        o[j] = f2bf(fmaxf(y, 0.f));
    }
    *(us8*)(h + i8) = o;
}

// graph-LN + ReLU + column-sum only (layer 2; h2 not needed afterwards)
__global__ void k_ln_colsum(const unsigned short* __restrict__ h, int n,
                            const float* __restrict__ st,
                            const float* __restrict__ g, const float* __restrict__ b,
                            float* __restrict__ colsum) {
    float mu = st[0] / (float)n;
    float var = st[1] / (float)n - mu * mu;
    var = var < 0.f ? 0.f : var;
    float inv = 1.0f / (sqrtf(var) + EPSV);
    int t = threadIdx.x;
    float gv = g[t], bv = b[t];
    float local = 0.f;
    int stride = gridDim.x * blockDim.x;   // multiple of 256 -> channel == t always
    for (int i = blockIdx.x * blockDim.x + t; i < n; i += stride) {
        float y = (bf2f(h[i]) - mu) * inv * gv + bv;
        local += fmaxf(y, 0.f);
    }
    atomicAdd(&colsum[t], local);
}

// ---------------- head: mean-pool @ Wf + bf -> LN(64) -> relu ----------------
__global__ void k_final(const float* __restrict__ colsum, const float* __restrict__ Wf,
                        const float* __restrict__ bf, const float* __restrict__ gx,
                        const float* __restrict__ bx, float* __restrict__ out) {
    __shared__ float p[256];
    int t = threadIdx.x;
    p[t] = colsum[t] * (1.0f / (float)NODES);
    __syncthreads();
    if (t < 64) {
        float acc = bf[t];
        for (int c = 0; c < 256; c++) acc = fmaf(p[c], Wf[c * 64 + t], acc);
        float sum = acc;
        for (int o = 32; o > 0; o >>= 1) sum += __shfl_xor(sum, o);
        float mu = sum * (1.0f / 64.0f);
        float d = acc - mu;
        float vs = d * d;
        for (int o = 32; o > 0; o >>= 1) vs += __shfl_xor(vs, o);
        float var = vs * (1.0f / 64.0f);
        float y = d * rsqrtf(var + EPSV) * gx[t] + bx[t];
        out[t] = fmaxf(y, 0.f);
    }
}

extern "C" void kernel_launch(void* const* d_in, const int* in_sizes, int n_in,
                              void* d_out, int out_size, void* d_ws, size_t ws_size,
                              hipStream_t stream) {
    const float* x   = (const float*)d_in[0];
    const int*   ei  = (const int*)d_in[1];
    const float* t1  = (const float*)d_in[2];
    const float* Wl1 = (const float*)d_in[3];
    const float* bl1 = (const float*)d_in[4];
    const float* Wr1 = (const float*)d_in[5];
    const float* g1  = (const float*)d_in[6];
    const float* be1 = (const float*)d_in[7];
    const float* t2  = (const float*)d_in[8];
    const float* Wl2 = (const float*)d_in[9];
    const float* bl2 = (const float*)d_in[10];
    const float* Wr2 = (const float*)d_in[11];
    const float* g2  = (const float*)d_in[12];
    const float* be2 = (const float*)d_in[13];
    const float* Wf  = (const float*)d_in[14];
    const float* bf  = (const float*)d_in[15];
    const float* gx  = (const float*)d_in[16];
    const float* bx  = (const float*)d_in[17];
    float* out = (float*)d_out;

    char* ws = (char*)d_ws;
    size_t off = 0;
    auto alloc = [&](size_t bytes) { size_t o = off; off = (off + bytes + 511) & ~511ull; return o; };
    size_t o_counts = alloc((size_t)NODES * 4);
    size_t o_cursor = alloc((size_t)NODES * 4);
    size_t o_acc    = alloc(4 * 4);
    size_t o_colsum = alloc(256 * 4);
    size_t zero_bytes = off;
    size_t o_offs = alloc((size_t)(NODES + 1) * 4);
    size_t o_csrc = alloc((size_t)EDGES * 4);
    size_t o_w1l  = alloc((size_t)512 * 256 * 2);
    size_t o_w1r  = alloc((size_t)512 * 256 * 2);
    size_t o_w2l  = alloc((size_t)256 * 512 * 2);
    size_t o_w2r  = alloc((size_t)256 * 512 * 2);
    size_t o_bufX = alloc((size_t)MPAD * 256 * 2);   // xb, later h2_pre (bf16)
    size_t o_agg  = alloc((size_t)MPAD * 512 * 2);   // agg1b / agg2b
    size_t o_h1   = alloc((size_t)MPAD * 512 * 2);   // h1 pre-LN bf16, LN'd in place

    int*   counts = (int*)(ws + o_counts);
    int*   cursor = (int*)(ws + o_cursor);
    float* acc    = (float*)(ws + o_acc);      // [0,1]=L1 stats, [2,3]=L2 stats
    float* colsum = (float*)(ws + o_colsum);
    int*   offs   = (int*)(ws + o_offs);
    int*   csrc   = (int*)(ws + o_csrc);
    unsigned short* w1lt = (unsigned short*)(ws + o_w1l);
    unsigned short* w1rt = (unsigned short*)(ws + o_w1r);
    unsigned short* w2lt = (unsigned short*)(ws + o_w2l);
    unsigned short* w2rt = (unsigned short*)(ws + o_w2r);
    unsigned short* xb   = (unsigned short*)(ws + o_bufX);
    unsigned short* h2p  = (unsigned short*)(ws + o_bufX);  // reuse after xb dead
    unsigned short* aggb = (unsigned short*)(ws + o_agg);
    unsigned short* h1   = (unsigned short*)(ws + o_h1);

    const int* src = ei;
    const int* dst = ei + EDGES;

    hipMemsetAsync(ws, 0, zero_bytes, stream);

    // CSR + precasts
    k_count<<<(EDGES + 255) / 256, 256, 0, stream>>>(dst, counts);
    k_scan<<<1, 256, 0, stream>>>(counts, offs);
    k_scatter<<<(EDGES + 255) / 256, 256, 0, stream>>>(src, dst, offs, cursor, csrc);
    k_cast<<<NODES * 256 / 4 / 256, 256, 0, stream>>>(x, xb);
    k_transpose_all<<<dim3(128, 1, 4), dim3(32, 8), 0, stream>>>(
        Wl1, Wr1, Wl2, Wr2, w1lt, w1rt, w2lt, w2rt);

    // ----- layer 1 -----
    k_agg<256, 8><<<(NODES + 3) / 4, 256, 0, stream>>>(xb, t1, offs, csrc, aggb);
    k_gemm_mfma<256, 512><<<dim3(MPAD / 128, 4), 256, 0, stream>>>(
        aggb, w1lt, xb, w1rt, bl1, h1, NODES, acc);
    k_ln_relu_b<512><<<NODES * 512 / 8 / 256, 256, 0, stream>>>(h1, NODES * 512, acc, g1, be1);

    // ----- layer 2 -----
    k_agg<512, 4><<<(NODES + 3) / 4, 256, 0, stream>>>(h1, t2, offs, csrc, aggb);
    k_gemm_mfma<512, 256><<<dim3(MPAD / 128, 2), 256, 0, stream>>>(
        aggb, w2lt, h1, w2rt, bl2, h2p, NODES, acc + 2);
    k_ln_colsum<<<1024, 256, 0, stream>>>(h2p, NODES * 256, acc + 2, g2, be2, colsum);

    // ----- head -----
    k_final<<<1, 256, 0, stream>>>(colsum, Wf, bf, gx, bx, out);
}